// Round 8
// baseline (176.563 us; speedup 1.0000x reference)
//
#include <hip/hip_runtime.h>

// B = in_sizes[0]/840, L=40, A=21. ONE THREAD PER ROW, reading its own row
// CONTIGUOUSLY as float4 (no LDS, no barriers, no fences). This removes the
// partial-cache-line overfetch of position-chunked staging (R4/R6 gap):
// every 128-B line is fully consumed from within one wave's load window.
// Body = 4 positions = 84 floats = 21 float4 (exact); register double-buffer
// A/B with compile-time names; v/j germline offsets are wave-uniform -> s_load.
#define LPOS 40
#define AA   21
#define ROWF (LPOS*AA)      // 840 floats per row
#define BODYP 4             // positions per body
#define BODYF (BODYP*AA)    // 84 floats = 21 float4
#define BODY4 (BODYF/4)     // 21 float4
#define NBODY (LPOS/BODYP)  // 10 bodies
#define NTHR 256

// Compile-time float4 element access (SROA-safe, no dynamic indexing).
#define EL(buf, i) (((i) & 3) == 0 ? buf[(i) >> 2].x : \
                    ((i) & 3) == 1 ? buf[(i) >> 2].y : \
                    ((i) & 3) == 2 ? buf[(i) >> 2].z : buf[(i) >> 2].w)

__global__ __launch_bounds__(NTHR) void cm_kernel(
    const float* __restrict__ x,
    const float* __restrict__ vg,
    const float* __restrict__ jg,
    float* __restrict__ out)
{
    const long long row = (long long)blockIdx.x * NTHR + threadIdx.x;
    const float4* xr = (const float4*)(x + row * ROWF);   // row*3360 B, 16B-aligned

    float4 bufA[BODY4], bufB[BODY4];

    // Compute body k (4 positions) from BUF; v/j offsets all compile-time
    // constants relative to k -> wave-uniform scalar loads.
    #define COMPUTE(k, BUF)                                                \
      {                                                                    \
        _Pragma("unroll")                                                  \
        for (int p = 0; p < BODYP; ++p) {                                  \
          float m = 0.f, jm = 0.f;                                         \
          _Pragma("unroll")                                                \
          for (int a = 0; a < AA; ++a) {                                   \
            const int i = p * AA + a;                                      \
            const float xv = EL(BUF, i);                                   \
            m  = fmaf(xv, vg[(k) * BODYF + i], m);                         \
            jm = fmaf(xv, jg[(k) * BODYF + i], jm);                        \
          }                                                                \
          run *= m; vsum += run; jsum += jm;                               \
        }                                                                  \
      }

    #define LOAD(k, BUF)                                                   \
      {                                                                    \
        _Pragma("unroll")                                                  \
        for (int i = 0; i < BODY4; ++i) BUF[i] = xr[(k) * BODY4 + i];      \
      }

    float run = 1.0f, vsum = 0.0f, jsum = 0.0f;

    LOAD(0, bufA)
    #pragma unroll
    for (int kk = 0; kk < NBODY / 2; ++kk) {
        const int k = 2 * kk;
        LOAD(k + 1, bufB)              // prefetch next body while computing A
        COMPUTE(k, bufA)
        if (k + 2 < NBODY) LOAD(k + 2, bufA)   // compile-time guard (unrolled)
        COMPUTE(k + 1, bufB)
    }

    ((float2*)out)[row] = make_float2(vsum, jsum);   // coalesced 8B store
}

extern "C" void kernel_launch(void* const* d_in, const int* in_sizes, int n_in,
                              void* d_out, int out_size, void* d_ws, size_t ws_size,
                              hipStream_t stream) {
    const float* x  = (const float*)d_in[0];
    const float* vg = (const float*)d_in[1];
    const float* jg = (const float*)d_in[2];
    float* out      = (float*)d_out;

    const int B    = in_sizes[0] / ROWF;   // 131072
    const int grid = B / NTHR;             // 512

    cm_kernel<<<grid, NTHR, 0, stream>>>(x, vg, jg, out);
}